// Round 4
// baseline (408.704 us; speedup 1.0000x reference)
//
#include <hip/hip_runtime.h>
#include <hip/hip_bf16.h>

// MHA: B=4, S=2048, D=1024, H=16, DH=64.  All matmuls via mfma_f32_16x16x32_bf16.
// ws (MB): WTq@0 WTk@2 WTv@4 WTo@6 | Qb@8 Kb@24 VT@40 | X@56 (q-bf16, then Xattn).
// key/value bf16 scratch lives in d_out (33.5MB), consumed before gemm_out writes it.

typedef __bf16 bf16x8 __attribute__((ext_vector_type(8)));
typedef float f32x4 __attribute__((ext_vector_type(4)));

#define GLOBAL_AS __attribute__((address_space(1)))
#define LDS_AS __attribute__((address_space(3)))

#if __has_builtin(__builtin_amdgcn_exp2f)
#define EXP2(x) __builtin_amdgcn_exp2f(x)
#else
#define EXP2(x) __expf((x) * 0.6931471805599453f)
#endif
#define QSCALE 0.18033688f   // 0.125 * log2(e): scores live in log2 domain

static __device__ __forceinline__ unsigned short f2bf(float f) {
    __bf16 h = (__bf16)f;                       // RNE
    return __builtin_bit_cast(unsigned short, h);
}

static __device__ __forceinline__ void gload_lds16(const void* g, void* l) {
    __builtin_amdgcn_global_load_lds((const GLOBAL_AS void*)g, (LDS_AS void*)l, 16, 0, 0);
}

// ---------------- fp32 -> bf16 bulk convert, 3 tensors in one launch (z selects)
__global__ __launch_bounds__(256) void cvt3(const float* __restrict__ q,
                                            const float* __restrict__ k,
                                            const float* __restrict__ v,
                                            unsigned short* __restrict__ dq,
                                            unsigned short* __restrict__ dk,
                                            unsigned short* __restrict__ dv, int n8) {
    const int z = blockIdx.z;
    const float* src = (z == 0) ? q : (z == 1) ? k : v;
    unsigned short* dst = (z == 0) ? dq : (z == 1) ? dk : dv;
    int i = blockIdx.x * 256 + threadIdx.x;
    if (i >= n8) return;
    const float4* s = (const float4*)src + 2 * (size_t)i;
    float4 v0 = s[0], v1 = s[1];
    unsigned short h[8] = {f2bf(v0.x), f2bf(v0.y), f2bf(v0.z), f2bf(v0.w),
                           f2bf(v1.x), f2bf(v1.y), f2bf(v1.z), f2bf(v1.w)};
    *(uint4*)(dst + 8 * (size_t)i) = *(const uint4*)h;
}

// ---------------- weight transpose: W fp32 [K=1024][N=1024] -> W^T bf16 [N][K]
__global__ void transpose_weights(const float* __restrict__ W0, const float* __restrict__ W1,
                                  const float* __restrict__ W2, const float* __restrict__ W3,
                                  unsigned short* __restrict__ T0, unsigned short* __restrict__ T1,
                                  unsigned short* __restrict__ T2, unsigned short* __restrict__ T3) {
    const float* W; unsigned short* T;
    switch (blockIdx.z) { case 0: W=W0; T=T0; break; case 1: W=W1; T=T1; break;
                          case 2: W=W2; T=T2; break; default: W=W3; T=T3; }
    __shared__ float tile[32][33];
    int tx = threadIdx.x, ty = threadIdx.y;
    int k0 = blockIdx.x * 32, n0 = blockIdx.y * 32;
#pragma unroll
    for (int j = 0; j < 4; j++) tile[ty + 8*j][tx] = W[(size_t)(k0 + ty + 8*j) * 1024 + n0 + tx];
    __syncthreads();
#pragma unroll
    for (int j = 0; j < 4; j++) T[(size_t)(n0 + ty + 8*j) * 1024 + k0 + tx] = f2bf(tile[tx][ty + 8*j]);
}

// ---------------- shared GEMM K-loop (m97 structure): 128x128 tile, BK=64, global_load_lds
static __device__ __forceinline__ void gemm_core(const unsigned short* __restrict__ A,
                                                 const unsigned short* __restrict__ BT,
                                                 unsigned short* Asm, unsigned short* Bsm,
                                                 int rowBase, int colBase, int t,
                                                 f32x4 acc[4][4]) {
    const int lane = t & 63, w = t >> 6;
    const int g = lane >> 4, r16 = lane & 15;
    const int wr = w >> 1, wc = w & 1;
    const int K = 1024;
    const int srow = t >> 3;
    const int scol = (t & 7) * 8;

    const unsigned short* srcA[4];
    const unsigned short* srcB[4];
#pragma unroll
    for (int j = 0; j < 4; j++) {
        srcA[j] = A  + (size_t)(rowBase + srow + 32 * j) * K + scol;
        srcB[j] = BT + (size_t)(colBase + srow + 32 * j) * K + scol;
    }
    unsigned short* dstA = Asm + 512 * w;
    unsigned short* dstB = Bsm + 512 * w;

    for (int k0 = 0; k0 < K; k0 += 64) {
        __syncthreads();
#pragma unroll
        for (int j = 0; j < 4; j++) {
            gload_lds16(srcA[j] + k0, dstA + 2048 * j);
            gload_lds16(srcB[j] + k0, dstB + 2048 * j);
        }
        __syncthreads();
#pragma unroll
        for (int ks = 0; ks < 2; ks++) {
            bf16x8 a[4], b[4];
#pragma unroll
            for (int m = 0; m < 4; m++) {
                int row = 64 * wr + 16 * m + r16;
                a[m] = *(const bf16x8*)(Asm + row * 64 + 32 * ks + 8 * g);
            }
#pragma unroll
            for (int n = 0; n < 4; n++) {
                int row = 64 * wc + 16 * n + r16;
                b[n] = *(const bf16x8*)(Bsm + row * 64 + 32 * ks + 8 * g);
            }
#pragma unroll
            for (int m = 0; m < 4; m++)
#pragma unroll
                for (int n = 0; n < 4; n++)
                    acc[m][n] = __builtin_amdgcn_mfma_f32_16x16x32_bf16(a[m], b[n], acc[m][n], 0, 0, 0);
        }
    }
}

// ---------------- fused Q/K/V projection GEMM (z: 0=Q scaled, 1=K, 2=V^T)
__global__ __launch_bounds__(256) void gemm_qkv(
        const unsigned short* __restrict__ Xq, const unsigned short* __restrict__ Xk,
        const unsigned short* __restrict__ Xv,
        const unsigned short* __restrict__ WTq, const unsigned short* __restrict__ WTk,
        const unsigned short* __restrict__ WTv,
        const float* __restrict__ bq, const float* __restrict__ bk, const float* __restrict__ bv,
        unsigned short* __restrict__ Qb, unsigned short* __restrict__ Kb,
        unsigned short* __restrict__ VT) {
    __shared__ alignas(16) unsigned short Asm[8192];
    __shared__ alignas(16) unsigned short Bsm[8192];
    const int z = blockIdx.z;
    const unsigned short* A  = (z == 0) ? Xq : (z == 1) ? Xk : Xv;
    const unsigned short* BT = (z == 0) ? WTq : (z == 1) ? WTk : WTv;
    const float* bias        = (z == 0) ? bq : (z == 1) ? bk : bv;
    const int rowBase = blockIdx.y * 128, colBase = blockIdx.x * 128;
    const int t = threadIdx.x;
    const int lane = t & 63, w = t >> 6;
    const int g = lane >> 4, r16 = lane & 15;
    const int wr = w >> 1, wc = w & 1;

    f32x4 acc[4][4] = {};
    gemm_core(A, BT, Asm, Bsm, rowBase, colBase, t, acc);

    float bv4[4];
#pragma unroll
    for (int n = 0; n < 4; n++) bv4[n] = bias[colBase + 64 * wc + 16 * n + r16];

#pragma unroll
    for (int m = 0; m < 4; m++) {
#pragma unroll
        for (int n = 0; n < 4; n++) {
#pragma unroll
            for (int i = 0; i < 4; i++) {
                int row = rowBase + 64 * wr + 16 * m + 4 * g + i;
                int col = colBase + 64 * wc + 16 * n + r16;
                float v = acc[m][n][i] + bv4[n];
                int bidx = row >> 11, s = row & 2047;
                int hidx = col >> 6, dh = col & 63;
                size_t bh = (size_t)(bidx * 16 + hidx);
                if (z == 0)      Qb[(bh * 2048 + s) * 64 + dh] = f2bf(v * QSCALE);
                else if (z == 1) Kb[(bh * 2048 + s) * 64 + dh] = f2bf(v);
                else             VT[(bh * 64 + dh) * 2048 + s] = f2bf(v);
            }
        }
    }
}

// ---------------- output projection GEMM: fp32 out
__global__ __launch_bounds__(256) void gemm_out(const unsigned short* __restrict__ A,
                                                const unsigned short* __restrict__ BT,
                                                const float* __restrict__ bias,
                                                float* __restrict__ Out) {
    __shared__ alignas(16) unsigned short Asm[8192];
    __shared__ alignas(16) unsigned short Bsm[8192];
    const int rowBase = blockIdx.y * 128, colBase = blockIdx.x * 128;
    const int t = threadIdx.x;
    const int lane = t & 63, w = t >> 6;
    const int g = lane >> 4, r16 = lane & 15;
    const int wr = w >> 1, wc = w & 1;

    f32x4 acc[4][4] = {};
    gemm_core(A, BT, Asm, Bsm, rowBase, colBase, t, acc);

    float bv4[4];
#pragma unroll
    for (int n = 0; n < 4; n++) bv4[n] = bias[colBase + 64 * wc + 16 * n + r16];

#pragma unroll
    for (int m = 0; m < 4; m++)
#pragma unroll
        for (int n = 0; n < 4; n++)
#pragma unroll
            for (int i = 0; i < 4; i++) {
                int row = rowBase + 64 * wr + 16 * m + 4 * g + i;
                int col = colBase + 64 * wc + 16 * n + r16;
                Out[(size_t)row * 1024 + col] = acc[m][n][i] + bv4[n];
            }
}

// ---------------- flash attention step for one q-state on the staged k-tile
static __device__ __forceinline__ void attn_step(
        const unsigned short* __restrict__ Ks, const unsigned short* __restrict__ Vs,
        const bf16x8 qfrag[2], f32x4 acco[4], float& m, float& lsum,
        int myq, int k0, bool diag,
        int g, int q16, int gh, int srcA, int srcB) {
    // S^T: accS[tt] holds D[krow = 16tt+4g+i][q = q16]  (scores in log2 domain)
    f32x4 accS[4] = {};
    __builtin_amdgcn_s_setprio(1);
#pragma unroll
    for (int ks = 0; ks < 2; ks++) {
#pragma unroll
        for (int tt = 0; tt < 4; tt++) {
            int row = 16 * tt + q16;
            bf16x8 ak = *(const bf16x8*)(Ks + row * 64 + ((4 * ks + g) ^ (row & 7)) * 8);
            accS[tt] = __builtin_amdgcn_mfma_f32_16x16x32_bf16(ak, qfrag[ks], accS[tt], 0, 0, 0);
        }
    }
    __builtin_amdgcn_s_setprio(0);

    float s[4][4];
#pragma unroll
    for (int tt = 0; tt < 4; tt++)
#pragma unroll
        for (int i = 0; i < 4; i++) {
            float v = accS[tt][i];
            if (diag) {
                int kg = k0 + 16 * tt + 4 * g + i;
                if (kg > myq) v = -1e30f;
            }
            s[tt][i] = v;
        }

    float pmax = s[0][0];
#pragma unroll
    for (int tt = 0; tt < 4; tt++)
#pragma unroll
        for (int i = 0; i < 4; i++) pmax = fmaxf(pmax, s[tt][i]);
    pmax = fmaxf(pmax, __shfl_xor(pmax, 16));
    pmax = fmaxf(pmax, __shfl_xor(pmax, 32));

    if (!__all(pmax <= m + 8.0f)) {          // defer-max (T13): skip rescale when growth small
        float mnew = fmaxf(m, pmax);
        float sc = EXP2(m - mnew);
        lsum *= sc;
#pragma unroll
        for (int i = 0; i < 4; i++) {
            float sci = __shfl(sc, 4 * g + i);
#pragma unroll
            for (int d = 0; d < 4; d++) acco[d][i] *= sci;
        }
        m = mnew;
    }

    float tsum = 0.f;
    float p[4][4];
#pragma unroll
    for (int tt = 0; tt < 4; tt++)
#pragma unroll
        for (int i = 0; i < 4; i++) { p[tt][i] = EXP2(s[tt][i] - m); tsum += p[tt][i]; }
    tsum += __shfl_xor(tsum, 16);
    tsum += __shfl_xor(tsum, 32);
    lsum += tsum;

    unsigned lo[4], hi[4];
#pragma unroll
    for (int tt = 0; tt < 4; tt++) {
        lo[tt] = (unsigned)f2bf(p[tt][0]) | ((unsigned)f2bf(p[tt][1]) << 16);
        hi[tt] = (unsigned)f2bf(p[tt][2]) | ((unsigned)f2bf(p[tt][3]) << 16);
    }

    // PV: two shuffle rounds (tt=2ks, 2ks+1); dest selects with its own gh after.
#pragma unroll
    for (int ks = 0; ks < 2; ks++) {
        unsigned xa0 = __shfl(lo[2 * ks], srcA);
        unsigned xa1 = __shfl(hi[2 * ks], srcA);
        unsigned xa2 = __shfl(lo[2 * ks], srcB);
        unsigned xa3 = __shfl(hi[2 * ks], srcB);
        unsigned ya0 = __shfl(lo[2 * ks + 1], srcA);
        unsigned ya1 = __shfl(hi[2 * ks + 1], srcA);
        unsigned ya2 = __shfl(lo[2 * ks + 1], srcB);
        unsigned ya3 = __shfl(hi[2 * ks + 1], srcB);
        uint4 pw;
        pw.x = gh ? ya0 : xa0;
        pw.y = gh ? ya1 : xa1;
        pw.z = gh ? ya2 : xa2;
        pw.w = gh ? ya3 : xa3;
        bf16x8 pfrag = __builtin_bit_cast(bf16x8, pw);
        __builtin_amdgcn_s_setprio(1);
#pragma unroll
        for (int d = 0; d < 4; d++) {
            int row = 16 * d + q16;
            bf16x8 vv = *(const bf16x8*)(Vs + row * 64 + ((4 * ks + g) ^ (row & 7)) * 8);
            acco[d] = __builtin_amdgcn_mfma_f32_16x16x32_bf16(pfrag, vv, acco[d], 0, 0, 0);
        }
        __builtin_amdgcn_s_setprio(0);
    }
}

// ---------------- flash attention, causal. Block bx processes q-tiles (bx, 31-bx)
// simultaneously over ONE k-tile stream (0..31-bx): staging/barriers shared.
__global__ __launch_bounds__(256) void attn_kernel(const unsigned short* __restrict__ Q,
                                                   const unsigned short* __restrict__ Kb,
                                                   const unsigned short* __restrict__ VT,
                                                   unsigned short* __restrict__ Xout) {
    __shared__ alignas(16) unsigned short Ksm[2][4096];
    __shared__ alignas(16) unsigned short Vsm[2][4096];
    const int t = threadIdx.x;
    const int lane = t & 63, w = t >> 6;
    const int g = lane >> 4, q16 = lane & 15;
    const int bh = blockIdx.y;
    const int b = bh >> 4, h = bh & 15;
    const int bx = blockIdx.x;
    const int qtA = bx, qtB = 31 - bx;
    const int myqA = qtA * 64 + 16 * w + q16;
    const int myqB = qtB * 64 + 16 * w + q16;

    // staging: LDS(row,s16) = global(row, s16^(row&7)); row = t/8 + 32j, slot t&7
    const int srow0 = t >> 3;
    const int ssrc = ((t & 7) ^ (srow0 & 7)) * 8;
    const unsigned short* srcK[2];
    const unsigned short* srcV[2];
#pragma unroll
    for (int j = 0; j < 2; j++) {
        int row = srow0 + 32 * j;
        srcK[j] = Kb + ((size_t)bh * 2048 + row) * 64 + ssrc;    // + 4096*kt
        srcV[j] = VT + ((size_t)bh * 64 + row) * 2048 + ssrc;    // + 64*kt
    }

    const int gh = g >> 1;
    const int g0 = 2 * (g & 1);
    const int srcA = 16 * g0 + q16, srcB = srcA + 16;

    bf16x8 qfA[2], qfB[2];
    {
        const uint4* qp = (const uint4*)(Q + ((size_t)bh * 2048 + myqA) * 64);
        qfA[0] = __builtin_bit_cast(bf16x8, qp[g]);
        qfA[1] = __builtin_bit_cast(bf16x8, qp[4 + g]);
        const uint4* qq = (const uint4*)(Q + ((size_t)bh * 2048 + myqB) * 64);
        qfB[0] = __builtin_bit_cast(bf16x8, qq[g]);
        qfB[1] = __builtin_bit_cast(bf16x8, qq[4 + g]);
    }

    f32x4 accoA[4] = {}, accoB[4] = {};
    float mA = -1e30f, lsA = 0.f, mB = -1e30f, lsB = 0.f;
    int cur = 0;

#pragma unroll
    for (int j = 0; j < 2; j++) {
        gload_lds16(srcK[j], &Ksm[0][512 * w + 2048 * j]);
        gload_lds16(srcV[j], &Vsm[0][512 * w + 2048 * j]);
    }
    __syncthreads();

    const int nkt = qtB + 1;
#pragma unroll 1
    for (int kt = 0; kt < nkt; kt++) {
        if (kt + 1 < nkt) {
            int nxt = cur ^ 1;
#pragma unroll
            for (int j = 0; j < 2; j++) {
                gload_lds16(srcK[j] + (size_t)(kt + 1) * 4096, &Ksm[nxt][512 * w + 2048 * j]);
                gload_lds16(srcV[j] + (size_t)(kt + 1) * 64,   &Vsm[nxt][512 * w + 2048 * j]);
            }
        }
        const unsigned short* Ks = Ksm[cur];
        const unsigned short* Vs = Vsm[cur];
        attn_step(Ks, Vs, qfB, accoB, mB, lsB, myqB, kt * 64, kt == qtB, g, q16, gh, srcA, srcB);
        if (kt <= qtA)
            attn_step(Ks, Vs, qfA, accoA, mA, lsA, myqA, kt * 64, kt == qtA, g, q16, gh, srcA, srcB);
        __syncthreads();
        cur ^= 1;
    }

    // write both states: lane holds O[q'=4g+i][dh=16d+q16]
#pragma unroll
    for (int i = 0; i < 4; i++) {
        float liB = __shfl(lsB, 4 * g + i);
        float invB = 1.f / liB;
        int rowB = qtB * 64 + 16 * w + 4 * g + i;
        float liA = __shfl(lsA, 4 * g + i);
        float invA = 1.f / liA;
        int rowA = qtA * 64 + 16 * w + 4 * g + i;
#pragma unroll
        for (int d = 0; d < 4; d++) {
            int col = h * 64 + 16 * d + q16;
            Xout[((size_t)b * 2048 + rowB) * 1024 + col] = f2bf(accoB[d][i] * invB);
            Xout[((size_t)b * 2048 + rowA) * 1024 + col] = f2bf(accoA[d][i] * invA);
        }
    }
}

extern "C" void kernel_launch(void* const* d_in, const int* in_sizes, int n_in,
                              void* d_out, int out_size, void* d_ws, size_t ws_size,
                              hipStream_t stream) {
    (void)in_sizes; (void)n_in; (void)out_size; (void)ws_size;
    const float* query = (const float*)d_in[0];
    const float* key   = (const float*)d_in[1];
    const float* value = (const float*)d_in[2];
    // d_in[3] = mask (causal tril) — implemented analytically
    const float* Wq = (const float*)d_in[4];
    const float* bq = (const float*)d_in[5];
    const float* Wk = (const float*)d_in[6];
    const float* bk = (const float*)d_in[7];
    const float* Wv = (const float*)d_in[8];
    const float* bv = (const float*)d_in[9];
    const float* Wo = (const float*)d_in[10];
    const float* bo = (const float*)d_in[11];

    char* base = (char*)d_ws;
    const size_t MB = 1u << 20;
    unsigned short* WTq = (unsigned short*)(base + 0 * MB);
    unsigned short* WTk = (unsigned short*)(base + 2 * MB);
    unsigned short* WTv = (unsigned short*)(base + 4 * MB);
    unsigned short* WTo = (unsigned short*)(base + 6 * MB);
    unsigned short* Qb  = (unsigned short*)(base + 8 * MB);
    unsigned short* Kbf = (unsigned short*)(base + 24 * MB);
    unsigned short* VTb = (unsigned short*)(base + 40 * MB);
    unsigned short* X   = (unsigned short*)(base + 56 * MB);   // q-bf16, then Xattn

    // key/value bf16 scratch in d_out (consumed by gemm_qkv before gemm_out writes d_out)
    unsigned short* Xk = (unsigned short*)d_out;
    unsigned short* Xv = Xk + (size_t)8192 * 1024;

    const int n8 = (8192 * 1024) / 8;

    transpose_weights<<<dim3(32, 32, 4), dim3(32, 8), 0, stream>>>(Wq, Wk, Wv, Wo, WTq, WTk, WTv, WTo);
    cvt3<<<dim3(4096, 1, 3), 256, 0, stream>>>(query, key, value, X, Xk, Xv, n8);
    gemm_qkv<<<dim3(8, 64, 3), 256, 0, stream>>>(X, Xk, Xv, WTq, WTk, WTv, bq, bk, bv, Qb, Kbf, VTb);
    attn_kernel<<<dim3(16, 64), 256, 0, stream>>>(Qb, Kbf, VTb, X);
    gemm_out<<<dim3(8, 64), 256, 0, stream>>>(X, WTo, bo, (float*)d_out);
}

// Round 6
// 373.654 us; speedup vs baseline: 1.0938x; 1.0938x over previous
//
#include <hip/hip_runtime.h>
#include <hip/hip_bf16.h>

// MHA: B=4, S=2048, D=1024, H=16, DH=64.  All matmuls via mfma_f32_16x16x32_bf16.
// ws (MB): WTq@0 WTk@2 WTv@4 WTo@6 | Qb@8 Kb@24 VT@40 | X@56 (q-bf16, then Xattn).
// key/value bf16 scratch lives in d_out (33.5MB), consumed before gemm_out writes it.

typedef __bf16 bf16x8 __attribute__((ext_vector_type(8)));
typedef float f32x4 __attribute__((ext_vector_type(4)));

#define GLOBAL_AS __attribute__((address_space(1)))
#define LDS_AS __attribute__((address_space(3)))

#if __has_builtin(__builtin_amdgcn_exp2f)
#define EXP2(x) __builtin_amdgcn_exp2f(x)
#else
#define EXP2(x) __expf((x) * 0.6931471805599453f)
#endif
#define QSCALE 0.18033688f   // 0.125 * log2(e): scores live in log2 domain

static __device__ __forceinline__ unsigned short f2bf(float f) {
    __bf16 h = (__bf16)f;                       // RNE
    return __builtin_bit_cast(unsigned short, h);
}

static __device__ __forceinline__ void gload_lds16(const void* g, void* l) {
    __builtin_amdgcn_global_load_lds((const GLOBAL_AS void*)g, (LDS_AS void*)l, 16, 0, 0);
}

// ---------------- fp32 -> bf16 bulk convert, 3 tensors in one launch (z selects)
__global__ __launch_bounds__(256) void cvt3(const float* __restrict__ q,
                                            const float* __restrict__ k,
                                            const float* __restrict__ v,
                                            unsigned short* __restrict__ dq,
                                            unsigned short* __restrict__ dk,
                                            unsigned short* __restrict__ dv, int n8) {
    const int z = blockIdx.z;
    const float* src = (z == 0) ? q : (z == 1) ? k : v;
    unsigned short* dst = (z == 0) ? dq : (z == 1) ? dk : dv;
    int i = blockIdx.x * 256 + threadIdx.x;
    if (i >= n8) return;
    const float4* s = (const float4*)src + 2 * (size_t)i;
    float4 v0 = s[0], v1 = s[1];
    unsigned short h[8] = {f2bf(v0.x), f2bf(v0.y), f2bf(v0.z), f2bf(v0.w),
                           f2bf(v1.x), f2bf(v1.y), f2bf(v1.z), f2bf(v1.w)};
    *(uint4*)(dst + 8 * (size_t)i) = *(const uint4*)h;
}

// ---------------- weight transpose: W fp32 [K=1024][N=1024] -> W^T bf16 [N][K]
__global__ void transpose_weights(const float* __restrict__ W0, const float* __restrict__ W1,
                                  const float* __restrict__ W2, const float* __restrict__ W3,
                                  unsigned short* __restrict__ T0, unsigned short* __restrict__ T1,
                                  unsigned short* __restrict__ T2, unsigned short* __restrict__ T3) {
    const float* W; unsigned short* T;
    switch (blockIdx.z) { case 0: W=W0; T=T0; break; case 1: W=W1; T=T1; break;
                          case 2: W=W2; T=T2; break; default: W=W3; T=T3; }
    __shared__ float tile[32][33];
    int tx = threadIdx.x, ty = threadIdx.y;
    int k0 = blockIdx.x * 32, n0 = blockIdx.y * 32;
#pragma unroll
    for (int j = 0; j < 4; j++) tile[ty + 8*j][tx] = W[(size_t)(k0 + ty + 8*j) * 1024 + n0 + tx];
    __syncthreads();
#pragma unroll
    for (int j = 0; j < 4; j++) T[(size_t)(n0 + ty + 8*j) * 1024 + k0 + tx] = f2bf(tile[tx][ty + 8*j]);
}

// ---------------- GEMM K-loop, 2-phase double-buffered: prefetch next BK=64 tile
// via global_load_lds BEFORE compute on current; ONE barrier per K-step.
static __device__ __forceinline__ void gemm_core(const unsigned short* __restrict__ A,
                                                 const unsigned short* __restrict__ BT,
                                                 unsigned short* Asm, unsigned short* Bsm,
                                                 int rowBase, int colBase, int t,
                                                 f32x4 acc[4][4]) {
    const int lane = t & 63, w = t >> 6;
    const int g = lane >> 4, r16 = lane & 15;
    const int wr = w >> 1, wc = w & 1;
    const int K = 1024;
    const int srow = t >> 3;
    const int scol = (t & 7) * 8;

    const unsigned short* srcA[4];
    const unsigned short* srcB[4];
#pragma unroll
    for (int j = 0; j < 4; j++) {
        srcA[j] = A  + (size_t)(rowBase + srow + 32 * j) * K + scol;
        srcB[j] = BT + (size_t)(colBase + srow + 32 * j) * K + scol;
    }
    unsigned short* dstA = Asm + 512 * w;   // + 8192*buf + 2048*j
    unsigned short* dstB = Bsm + 512 * w;

    // prologue: stage tile 0 into buffer 0
#pragma unroll
    for (int j = 0; j < 4; j++) {
        gload_lds16(srcA[j], dstA + 2048 * j);
        gload_lds16(srcB[j], dstB + 2048 * j);
    }
    __syncthreads();

    int cur = 0;
    for (int k0 = 0; k0 < K; k0 += 64) {
        if (k0 + 64 < K) {   // prefetch next tile into the other buffer
            unsigned short* dA = dstA + (cur ^ 1) * 8192;
            unsigned short* dB = dstB + (cur ^ 1) * 8192;
#pragma unroll
            for (int j = 0; j < 4; j++) {
                gload_lds16(srcA[j] + k0 + 64, dA + 2048 * j);
                gload_lds16(srcB[j] + k0 + 64, dB + 2048 * j);
            }
        }
        const unsigned short* As = Asm + cur * 8192;
        const unsigned short* Bs = Bsm + cur * 8192;
#pragma unroll
        for (int ks = 0; ks < 2; ks++) {
            bf16x8 a[4], b[4];
#pragma unroll
            for (int m = 0; m < 4; m++) {
                int row = 64 * wr + 16 * m + r16;
                a[m] = *(const bf16x8*)(As + row * 64 + 32 * ks + 8 * g);
            }
#pragma unroll
            for (int n = 0; n < 4; n++) {
                int row = 64 * wc + 16 * n + r16;
                b[n] = *(const bf16x8*)(Bs + row * 64 + 32 * ks + 8 * g);
            }
#pragma unroll
            for (int m = 0; m < 4; m++)
#pragma unroll
                for (int n = 0; n < 4; n++)
                    acc[m][n] = __builtin_amdgcn_mfma_f32_16x16x32_bf16(a[m], b[n], acc[m][n], 0, 0, 0);
        }
        __syncthreads();   // drains prefetch vmcnt + protects buffer swap
        cur ^= 1;
    }
}

// ---------------- fused Q/K/V projection GEMM (z: 0=Q scaled, 1=K, 2=V^T)
__global__ __launch_bounds__(256) void gemm_qkv(
        const unsigned short* __restrict__ Xq, const unsigned short* __restrict__ Xk,
        const unsigned short* __restrict__ Xv,
        const unsigned short* __restrict__ WTq, const unsigned short* __restrict__ WTk,
        const unsigned short* __restrict__ WTv,
        const float* __restrict__ bq, const float* __restrict__ bk, const float* __restrict__ bv,
        unsigned short* __restrict__ Qb, unsigned short* __restrict__ Kb,
        unsigned short* __restrict__ VT) {
    __shared__ alignas(16) unsigned short Asm[2 * 8192];
    __shared__ alignas(16) unsigned short Bsm[2 * 8192];
    const int z = blockIdx.z;
    const unsigned short* A  = (z == 0) ? Xq : (z == 1) ? Xk : Xv;
    const unsigned short* BT = (z == 0) ? WTq : (z == 1) ? WTk : WTv;
    const float* bias        = (z == 0) ? bq : (z == 1) ? bk : bv;
    const int rowBase = blockIdx.y * 128, colBase = blockIdx.x * 128;
    const int t = threadIdx.x;
    const int lane = t & 63, w = t >> 6;
    const int g = lane >> 4, r16 = lane & 15;
    const int wr = w >> 1, wc = w & 1;

    f32x4 acc[4][4] = {};
    gemm_core(A, BT, Asm, Bsm, rowBase, colBase, t, acc);

    float bv4[4];
#pragma unroll
    for (int n = 0; n < 4; n++) bv4[n] = bias[colBase + 64 * wc + 16 * n + r16];

#pragma unroll
    for (int m = 0; m < 4; m++) {
#pragma unroll
        for (int n = 0; n < 4; n++) {
#pragma unroll
            for (int i = 0; i < 4; i++) {
                int row = rowBase + 64 * wr + 16 * m + 4 * g + i;
                int col = colBase + 64 * wc + 16 * n + r16;
                float v = acc[m][n][i] + bv4[n];
                int bidx = row >> 11, s = row & 2047;
                int hidx = col >> 6, dh = col & 63;
                size_t bh = (size_t)(bidx * 16 + hidx);
                if (z == 0)      Qb[(bh * 2048 + s) * 64 + dh] = f2bf(v * QSCALE);
                else if (z == 1) Kb[(bh * 2048 + s) * 64 + dh] = f2bf(v);
                else             VT[(bh * 64 + dh) * 2048 + s] = f2bf(v);
            }
        }
    }
}

// ---------------- output projection GEMM: fp32 out
__global__ __launch_bounds__(256) void gemm_out(const unsigned short* __restrict__ A,
                                                const unsigned short* __restrict__ BT,
                                                const float* __restrict__ bias,
                                                float* __restrict__ Out) {
    __shared__ alignas(16) unsigned short Asm[2 * 8192];
    __shared__ alignas(16) unsigned short Bsm[2 * 8192];
    const int rowBase = blockIdx.y * 128, colBase = blockIdx.x * 128;
    const int t = threadIdx.x;
    const int lane = t & 63, w = t >> 6;
    const int g = lane >> 4, r16 = lane & 15;
    const int wr = w >> 1, wc = w & 1;

    f32x4 acc[4][4] = {};
    gemm_core(A, BT, Asm, Bsm, rowBase, colBase, t, acc);

    float bv4[4];
#pragma unroll
    for (int n = 0; n < 4; n++) bv4[n] = bias[colBase + 64 * wc + 16 * n + r16];

#pragma unroll
    for (int m = 0; m < 4; m++)
#pragma unroll
        for (int n = 0; n < 4; n++)
#pragma unroll
            for (int i = 0; i < 4; i++) {
                int row = rowBase + 64 * wr + 16 * m + 4 * g + i;
                int col = colBase + 64 * wc + 16 * n + r16;
                Out[(size_t)row * 1024 + col] = acc[m][n][i] + bv4[n];
            }
}

// ---------------- flash attention step for one q-state on the staged k-tile
static __device__ __forceinline__ void attn_step(
        const unsigned short* __restrict__ Ks, const unsigned short* __restrict__ Vs,
        const bf16x8 qfrag[2], f32x4 acco[4], float& m, float& lsum,
        int myq, int k0, bool diag,
        int g, int q16, int gh, int srcA, int srcB) {
    // S^T: accS[tt] holds D[krow = 16tt+4g+i][q = q16]  (scores in log2 domain)
    f32x4 accS[4] = {};
    __builtin_amdgcn_s_setprio(1);
#pragma unroll
    for (int ks = 0; ks < 2; ks++) {
#pragma unroll
        for (int tt = 0; tt < 4; tt++) {
            int row = 16 * tt + q16;
            bf16x8 ak = *(const bf16x8*)(Ks + row * 64 + ((4 * ks + g) ^ (row & 7)) * 8);
            accS[tt] = __builtin_amdgcn_mfma_f32_16x16x32_bf16(ak, qfrag[ks], accS[tt], 0, 0, 0);
        }
    }
    __builtin_amdgcn_s_setprio(0);

    float s[4][4];
#pragma unroll
    for (int tt = 0; tt < 4; tt++)
#pragma unroll
        for (int i = 0; i < 4; i++) {
            float v = accS[tt][i];
            if (diag) {
                int kg = k0 + 16 * tt + 4 * g + i;
                if (kg > myq) v = -1e30f;
            }
            s[tt][i] = v;
        }

    float pmax = s[0][0];
#pragma unroll
    for (int tt = 0; tt < 4; tt++)
#pragma unroll
        for (int i = 0; i < 4; i++) pmax = fmaxf(pmax, s[tt][i]);
    pmax = fmaxf(pmax, __shfl_xor(pmax, 16));
    pmax = fmaxf(pmax, __shfl_xor(pmax, 32));

    if (!__all(pmax <= m + 8.0f)) {          // defer-max (T13): skip rescale when growth small
        float mnew = fmaxf(m, pmax);
        float sc = EXP2(m - mnew);
        lsum *= sc;
#pragma unroll
        for (int i = 0; i < 4; i++) {
            float sci = __shfl(sc, 4 * g + i);
#pragma unroll
            for (int d = 0; d < 4; d++) acco[d][i] *= sci;
        }
        m = mnew;
    }

    float tsum = 0.f;
    float p[4][4];
#pragma unroll
    for (int tt = 0; tt < 4; tt++)
#pragma unroll
        for (int i = 0; i < 4; i++) { p[tt][i] = EXP2(s[tt][i] - m); tsum += p[tt][i]; }
    tsum += __shfl_xor(tsum, 16);
    tsum += __shfl_xor(tsum, 32);
    lsum += tsum;

    unsigned lo[4], hi[4];
#pragma unroll
    for (int tt = 0; tt < 4; tt++) {
        lo[tt] = (unsigned)f2bf(p[tt][0]) | ((unsigned)f2bf(p[tt][1]) << 16);
        hi[tt] = (unsigned)f2bf(p[tt][2]) | ((unsigned)f2bf(p[tt][3]) << 16);
    }

    // PV: two shuffle rounds (tt=2ks, 2ks+1); dest selects with its own gh after.
#pragma unroll
    for (int ks = 0; ks < 2; ks++) {
        unsigned xa0 = __shfl(lo[2 * ks], srcA);
        unsigned xa1 = __shfl(hi[2 * ks], srcA);
        unsigned xa2 = __shfl(lo[2 * ks], srcB);
        unsigned xa3 = __shfl(hi[2 * ks], srcB);
        unsigned ya0 = __shfl(lo[2 * ks + 1], srcA);
        unsigned ya1 = __shfl(hi[2 * ks + 1], srcA);
        unsigned ya2 = __shfl(lo[2 * ks + 1], srcB);
        unsigned ya3 = __shfl(hi[2 * ks + 1], srcB);
        uint4 pw;
        pw.x = gh ? ya0 : xa0;
        pw.y = gh ? ya1 : xa1;
        pw.z = gh ? ya2 : xa2;
        pw.w = gh ? ya3 : xa3;
        bf16x8 pfrag = __builtin_bit_cast(bf16x8, pw);
        __builtin_amdgcn_s_setprio(1);
#pragma unroll
        for (int d = 0; d < 4; d++) {
            int row = 16 * d + q16;
            bf16x8 vv = *(const bf16x8*)(Vs + row * 64 + ((4 * ks + g) ^ (row & 7)) * 8);
            acco[d] = __builtin_amdgcn_mfma_f32_16x16x32_bf16(pfrag, vv, acco[d], 0, 0, 0);
        }
        __builtin_amdgcn_s_setprio(0);
    }
}

// ---------------- flash attention, causal. Block bx runs q-tiles bx then 31-bx
// SEQUENTIALLY (uniform 33 k-steps/block); K/V double-buffered via global_load_lds
// with pre-swizzled source; XOR-swizzled reads.
__global__ __launch_bounds__(256) void attn_kernel(const unsigned short* __restrict__ Q,
                                                   const unsigned short* __restrict__ Kb,
                                                   const unsigned short* __restrict__ VT,
                                                   unsigned short* __restrict__ Xout) {
    __shared__ alignas(16) unsigned short Ksm[2][4096];
    __shared__ alignas(16) unsigned short Vsm[2][4096];
    const int t = threadIdx.x;
    const int lane = t & 63, w = t >> 6;
    const int g = lane >> 4, q16 = lane & 15;
    const int bh = blockIdx.y;
    const int b = bh >> 4, h = bh & 15;

    // staging: LDS(row,s16) = global(row, s16^(row&7)); row = t/8 + 32j, slot t&7
    const int srow0 = t >> 3;
    const int ssrc = ((t & 7) ^ (srow0 & 7)) * 8;
    const unsigned short* srcK[2];
    const unsigned short* srcV[2];
#pragma unroll
    for (int j = 0; j < 2; j++) {
        int row = srow0 + 32 * j;
        srcK[j] = Kb + ((size_t)bh * 2048 + row) * 64 + ssrc;    // + 4096*kt
        srcV[j] = VT + ((size_t)bh * 64 + row) * 2048 + ssrc;    // + 64*kt
    }

    const int gh = g >> 1;
    const int g0 = 2 * (g & 1);
    const int srcA = 16 * g0 + q16, srcB = srcA + 16;

#pragma unroll 1
    for (int ph = 0; ph < 2; ph++) {
        const int qt = ph ? (31 - (int)blockIdx.x) : (int)blockIdx.x;
        const int q0 = qt * 64;
        const int myq = q0 + 16 * w + q16;
        const int nkt = qt + 1;

        bf16x8 qfrag[2];
        {
            const uint4* qp = (const uint4*)(Q + ((size_t)bh * 2048 + myq) * 64);
            qfrag[0] = __builtin_bit_cast(bf16x8, qp[g]);
            qfrag[1] = __builtin_bit_cast(bf16x8, qp[4 + g]);
        }

        f32x4 acco[4] = {};
        float m = -1e30f, lsum = 0.f;
        int cur = 0;

        // prologue: stage tile 0 into buffer 0
#pragma unroll
        for (int j = 0; j < 2; j++) {
            gload_lds16(srcK[j], &Ksm[0][512 * w + 2048 * j]);
            gload_lds16(srcV[j], &Vsm[0][512 * w + 2048 * j]);
        }
        __syncthreads();

        for (int kt = 0; kt < nkt; kt++) {
            if (kt + 1 < nkt) {   // prefetch next tile into the other buffer
                int nxt = cur ^ 1;
#pragma unroll
                for (int j = 0; j < 2; j++) {
                    gload_lds16(srcK[j] + (size_t)(kt + 1) * 4096, &Ksm[nxt][512 * w + 2048 * j]);
                    gload_lds16(srcV[j] + (size_t)(kt + 1) * 64,   &Vsm[nxt][512 * w + 2048 * j]);
                }
            }
            attn_step(Ksm[cur], Vsm[cur], qfrag, acco, m, lsum,
                      myq, kt * 64, kt == nkt - 1, g, q16, gh, srcA, srcB);
            __syncthreads();   // drains prefetch vmcnt + protects buffer swap
            cur ^= 1;
        }

        // normalize and write x[B,S,D] bf16: lane holds O[q'=4g+i][dh=16d+q16]
#pragma unroll
        for (int i = 0; i < 4; i++) {
            float li = __shfl(lsum, 4 * g + i);
            float inv = 1.f / li;
            int row = q0 + 16 * w + 4 * g + i;
#pragma unroll
            for (int d = 0; d < 4; d++) {
                int col = h * 64 + 16 * d + q16;
                Xout[((size_t)b * 2048 + row) * 1024 + col] = f2bf(acco[d][i] * inv);
            }
        }
        __syncthreads();   // phase boundary: buffers reused from scratch
    }
}

extern "C" void kernel_launch(void* const* d_in, const int* in_sizes, int n_in,
                              void* d_out, int out_size, void* d_ws, size_t ws_size,
                              hipStream_t stream) {
    (void)in_sizes; (void)n_in; (void)out_size; (void)ws_size;
    const float* query = (const float*)d_in[0];
    const float* key   = (const float*)d_in[1];
    const float* value = (const float*)d_in[2];
    // d_in[3] = mask (causal tril) — implemented analytically
    const float* Wq = (const float*)d_in[4];
    const float* bq = (const float*)d_in[5];
    const float* Wk = (const float*)d_in[6];
    const float* bk = (const float*)d_in[7];
    const float* Wv = (const float*)d_in[8];
    const float* bv = (const float*)d_in[9];
    const float* Wo = (const float*)d_in[10];
    const float* bo = (const float*)d_in[11];

    char* base = (char*)d_ws;
    const size_t MB = 1u << 20;
    unsigned short* WTq = (unsigned short*)(base + 0 * MB);
    unsigned short* WTk = (unsigned short*)(base + 2 * MB);
    unsigned short* WTv = (unsigned short*)(base + 4 * MB);
    unsigned short* WTo = (unsigned short*)(base + 6 * MB);
    unsigned short* Qb  = (unsigned short*)(base + 8 * MB);
    unsigned short* Kbf = (unsigned short*)(base + 24 * MB);
    unsigned short* VTb = (unsigned short*)(base + 40 * MB);
    unsigned short* X   = (unsigned short*)(base + 56 * MB);   // q-bf16, then Xattn

    // key/value bf16 scratch in d_out (consumed by gemm_qkv before gemm_out writes d_out)
    unsigned short* Xk = (unsigned short*)d_out;
    unsigned short* Xv = Xk + (size_t)8192 * 1024;

    const int n8 = (8192 * 1024) / 8;

    transpose_weights<<<dim3(32, 32, 4), dim3(32, 8), 0, stream>>>(Wq, Wk, Wv, Wo, WTq, WTk, WTv, WTo);
    cvt3<<<dim3(4096, 1, 3), 256, 0, stream>>>(query, key, value, X, Xk, Xv, n8);
    gemm_qkv<<<dim3(8, 64, 3), 256, 0, stream>>>(X, Xk, Xv, WTq, WTk, WTv, bq, bk, bv, Qb, Kbf, VTb);
    attn_kernel<<<dim3(16, 64), 256, 0, stream>>>(Qb, Kbf, VTb, X);
    gemm_out<<<dim3(8, 64), 256, 0, stream>>>(X, WTo, bo, (float*)d_out);
}

// Round 8
// 344.174 us; speedup vs baseline: 1.1875x; 1.0857x over previous
//
#include <hip/hip_runtime.h>
#include <hip/hip_bf16.h>

// MHA: B=4, S=2048, D=1024, H=16, DH=64.  All matmuls via mfma_f32_16x16x32_bf16.
// ws (MB): WTq@0 WTk@2 WTv@4 WTo@6 | Qb@8 Kb@24 VT@40 | X@56 (q-bf16, then Xattn).
// key/value bf16 scratch lives in d_out (33.5MB), consumed before gemm_out writes it.

typedef __bf16 bf16x8 __attribute__((ext_vector_type(8)));
typedef float f32x4 __attribute__((ext_vector_type(4)));

#define GLOBAL_AS __attribute__((address_space(1)))
#define LDS_AS __attribute__((address_space(3)))

#if __has_builtin(__builtin_amdgcn_exp2f)
#define EXP2(x) __builtin_amdgcn_exp2f(x)
#else
#define EXP2(x) __expf((x) * 0.6931471805599453f)
#endif
#define QSCALE 0.18033688f   // 0.125 * log2(e): scores live in log2 domain

static __device__ __forceinline__ unsigned short f2bf(float f) {
    __bf16 h = (__bf16)f;                       // RNE
    return __builtin_bit_cast(unsigned short, h);
}

static __device__ __forceinline__ void gload_lds16(const void* g, void* l) {
    __builtin_amdgcn_global_load_lds((const GLOBAL_AS void*)g, (LDS_AS void*)l, 16, 0, 0);
}

// ---------------- fp32 -> bf16 bulk convert, 3 tensors in one launch (z selects)
__global__ __launch_bounds__(256) void cvt3(const float* __restrict__ q,
                                            const float* __restrict__ k,
                                            const float* __restrict__ v,
                                            unsigned short* __restrict__ dq,
                                            unsigned short* __restrict__ dk,
                                            unsigned short* __restrict__ dv, int n8) {
    const int z = blockIdx.z;
    const float* src = (z == 0) ? q : (z == 1) ? k : v;
    unsigned short* dst = (z == 0) ? dq : (z == 1) ? dk : dv;
    int i = blockIdx.x * 256 + threadIdx.x;
    if (i >= n8) return;
    const float4* s = (const float4*)src + 2 * (size_t)i;
    float4 v0 = s[0], v1 = s[1];
    unsigned short h[8] = {f2bf(v0.x), f2bf(v0.y), f2bf(v0.z), f2bf(v0.w),
                           f2bf(v1.x), f2bf(v1.y), f2bf(v1.z), f2bf(v1.w)};
    *(uint4*)(dst + 8 * (size_t)i) = *(const uint4*)h;
}

// ---------------- weight transpose: W fp32 [K=1024][N=1024] -> W^T bf16 [N][K]
__global__ void transpose_weights(const float* __restrict__ W0, const float* __restrict__ W1,
                                  const float* __restrict__ W2, const float* __restrict__ W3,
                                  unsigned short* __restrict__ T0, unsigned short* __restrict__ T1,
                                  unsigned short* __restrict__ T2, unsigned short* __restrict__ T3) {
    const float* W; unsigned short* T;
    switch (blockIdx.z) { case 0: W=W0; T=T0; break; case 1: W=W1; T=T1; break;
                          case 2: W=W2; T=T2; break; default: W=W3; T=T3; }
    __shared__ float tile[32][33];
    int tx = threadIdx.x, ty = threadIdx.y;
    int k0 = blockIdx.x * 32, n0 = blockIdx.y * 32;
#pragma unroll
    for (int j = 0; j < 4; j++) tile[ty + 8*j][tx] = W[(size_t)(k0 + ty + 8*j) * 1024 + n0 + tx];
    __syncthreads();
#pragma unroll
    for (int j = 0; j < 4; j++) T[(size_t)(n0 + ty + 8*j) * 1024 + k0 + tx] = f2bf(tile[tx][ty + 8*j]);
}

// ---------------- GEMM K-loop, 2-phase double-buffered + T2 XOR-swizzled LDS.
// LDS(row, slot16B) = global(row, slot ^ (row&7)); gload_lds dest stays linear,
// source col is pre-swizzled (rule #21: both-sides-or-neither).
static __device__ __forceinline__ void gemm_core(const unsigned short* __restrict__ A,
                                                 const unsigned short* __restrict__ BT,
                                                 unsigned short* Asm, unsigned short* Bsm,
                                                 int rowBase, int colBase, int t,
                                                 f32x4 acc[4][4]) {
    const int lane = t & 63, w = t >> 6;
    const int g = lane >> 4, r16 = lane & 15;
    const int wr = w >> 1, wc = w & 1;
    const int K = 1024;
    const int srow = t >> 3;                           // 0..31 (+32j); row&7 = (t>>3)&7
    const int scol = ((t & 7) ^ ((t >> 3) & 7)) * 8;   // pre-swizzled source col

    const unsigned short* srcA[4];
    const unsigned short* srcB[4];
#pragma unroll
    for (int j = 0; j < 4; j++) {
        srcA[j] = A  + (size_t)(rowBase + srow + 32 * j) * K + scol;
        srcB[j] = BT + (size_t)(colBase + srow + 32 * j) * K + scol;
    }
    unsigned short* dstA = Asm + 512 * w;   // + 8192*buf + 2048*j (linear dest)
    unsigned short* dstB = Bsm + 512 * w;

    // prologue: stage tile 0 into buffer 0
#pragma unroll
    for (int j = 0; j < 4; j++) {
        gload_lds16(srcA[j], dstA + 2048 * j);
        gload_lds16(srcB[j], dstB + 2048 * j);
    }
    __syncthreads();

    int cur = 0;
    for (int k0 = 0; k0 < K; k0 += 64) {
        if (k0 + 64 < K) {   // prefetch next tile into the other buffer
            unsigned short* dA = dstA + (cur ^ 1) * 8192;
            unsigned short* dB = dstB + (cur ^ 1) * 8192;
#pragma unroll
            for (int j = 0; j < 4; j++) {
                gload_lds16(srcA[j] + k0 + 64, dA + 2048 * j);
                gload_lds16(srcB[j] + k0 + 64, dB + 2048 * j);
            }
        }
        const unsigned short* As = Asm + cur * 8192;
        const unsigned short* Bs = Bsm + cur * 8192;
#pragma unroll
        for (int ks = 0; ks < 2; ks++) {
            bf16x8 a[4], b[4];
#pragma unroll
            for (int m = 0; m < 4; m++) {
                int row = 64 * wr + 16 * m + r16;      // row&7 = r16&7
                a[m] = *(const bf16x8*)(As + row * 64 + ((4 * ks + g) ^ (row & 7)) * 8);
            }
#pragma unroll
            for (int n = 0; n < 4; n++) {
                int row = 64 * wc + 16 * n + r16;
                b[n] = *(const bf16x8*)(Bs + row * 64 + ((4 * ks + g) ^ (row & 7)) * 8);
            }
#pragma unroll
            for (int m = 0; m < 4; m++)
#pragma unroll
                for (int n = 0; n < 4; n++)
                    acc[m][n] = __builtin_amdgcn_mfma_f32_16x16x32_bf16(a[m], b[n], acc[m][n], 0, 0, 0);
        }
        __syncthreads();   // drains prefetch vmcnt + protects buffer swap
        cur ^= 1;
    }
}

// ---------------- fused Q/K/V projection GEMM (z: 0=Q scaled, 1=K, 2=V^T)
__global__ __launch_bounds__(256) void gemm_qkv(
        const unsigned short* __restrict__ Xq, const unsigned short* __restrict__ Xk,
        const unsigned short* __restrict__ Xv,
        const unsigned short* __restrict__ WTq, const unsigned short* __restrict__ WTk,
        const unsigned short* __restrict__ WTv,
        const float* __restrict__ bq, const float* __restrict__ bk, const float* __restrict__ bv,
        unsigned short* __restrict__ Qb, unsigned short* __restrict__ Kb,
        unsigned short* __restrict__ VT) {
    __shared__ alignas(16) unsigned short smem[32768];   // A dbuf | B dbuf; reused for V^T transpose
    unsigned short* Asm = smem;
    unsigned short* Bsm = smem + 16384;
    const int z = blockIdx.z;
    const unsigned short* A  = (z == 0) ? Xq : (z == 1) ? Xk : Xv;
    const unsigned short* BT = (z == 0) ? WTq : (z == 1) ? WTk : WTv;
    const float* bias        = (z == 0) ? bq : (z == 1) ? bk : bv;
    const int rowBase = blockIdx.y * 128, colBase = blockIdx.x * 128;
    const int t = threadIdx.x;
    const int lane = t & 63, w = t >> 6;
    const int g = lane >> 4, r16 = lane & 15;
    const int wr = w >> 1, wc = w & 1;

    f32x4 acc[4][4] = {};
    gemm_core(A, BT, Asm, Bsm, rowBase, colBase, t, acc);

    float bv4[4];
#pragma unroll
    for (int n = 0; n < 4; n++) bv4[n] = bias[colBase + 64 * wc + 16 * n + r16];

    if (z == 2) {
        // V^T epilogue: transpose 128x128 tile in LDS (padded stride), coalesced stores.
        const int TS = 136;   // pad: breaks 256B-stride bank pattern; rows stay 16B-aligned
        unsigned short* Tsm = smem;   // 128*136*2B = 34.8KB <= 64KB (K-loop done)
#pragma unroll
        for (int m = 0; m < 4; m++) {
#pragma unroll
            for (int n = 0; n < 4; n++) {
                int c = 64 * wc + 16 * n + r16;            // d-dim local
                int r = 64 * wr + 16 * m + 4 * g;          // s-dim local (i = 0..3)
                unsigned short pk[4];
#pragma unroll
                for (int i = 0; i < 4; i++) pk[i] = f2bf(acc[m][n][i] + bv4[n]);
                *(uint2*)(Tsm + c * TS + r) = *(const uint2*)pk;   // 8B, aligned (r%4==0)
            }
        }
        __syncthreads();
        const int bidx = rowBase >> 11;
        const int sBase = rowBase & 2047;   // within-batch seq position (BUGFIX R7: was rowBase)
        const int sloc = (t & 15) * 8;
#pragma unroll
        for (int jj = 0; jj < 8; jj++) {
            int dloc = (t >> 4) + 16 * jj;
            uint4 v = *(const uint4*)(Tsm + dloc * TS + sloc);
            int col = colBase + dloc;
            int hidx = col >> 6, dh = col & 63;
            *(uint4*)&VT[(((size_t)(bidx * 16 + hidx)) * 64 + dh) * 2048 + sBase + sloc] = v;
        }
    } else {
#pragma unroll
        for (int m = 0; m < 4; m++) {
#pragma unroll
            for (int n = 0; n < 4; n++) {
#pragma unroll
                for (int i = 0; i < 4; i++) {
                    int row = rowBase + 64 * wr + 16 * m + 4 * g + i;
                    int col = colBase + 64 * wc + 16 * n + r16;
                    float v = acc[m][n][i] + bv4[n];
                    int bidx = row >> 11, s = row & 2047;
                    int hidx = col >> 6, dh = col & 63;
                    size_t bh = (size_t)(bidx * 16 + hidx);
                    if (z == 0) Qb[(bh * 2048 + s) * 64 + dh] = f2bf(v * QSCALE);
                    else        Kb[(bh * 2048 + s) * 64 + dh] = f2bf(v);
                }
            }
        }
    }
}

// ---------------- output projection GEMM: fp32 out
__global__ __launch_bounds__(256) void gemm_out(const unsigned short* __restrict__ A,
                                                const unsigned short* __restrict__ BT,
                                                const float* __restrict__ bias,
                                                float* __restrict__ Out) {
    __shared__ alignas(16) unsigned short smem[32768];
    unsigned short* Asm = smem;
    unsigned short* Bsm = smem + 16384;
    const int rowBase = blockIdx.y * 128, colBase = blockIdx.x * 128;
    const int t = threadIdx.x;
    const int lane = t & 63, w = t >> 6;
    const int g = lane >> 4, r16 = lane & 15;
    const int wr = w >> 1, wc = w & 1;

    f32x4 acc[4][4] = {};
    gemm_core(A, BT, Asm, Bsm, rowBase, colBase, t, acc);

    float bv4[4];
#pragma unroll
    for (int n = 0; n < 4; n++) bv4[n] = bias[colBase + 64 * wc + 16 * n + r16];

#pragma unroll
    for (int m = 0; m < 4; m++)
#pragma unroll
        for (int n = 0; n < 4; n++)
#pragma unroll
            for (int i = 0; i < 4; i++) {
                int row = rowBase + 64 * wr + 16 * m + 4 * g + i;
                int col = colBase + 64 * wc + 16 * n + r16;
                Out[(size_t)row * 1024 + col] = acc[m][n][i] + bv4[n];
            }
}

// ---------------- flash attention step for one q-state on the staged k-tile
static __device__ __forceinline__ void attn_step(
        const unsigned short* __restrict__ Ks, const unsigned short* __restrict__ Vs,
        const bf16x8 qfrag[2], f32x4 acco[4], float& m, float& lsum,
        int myq, int k0, bool diag,
        int g, int q16, int gh, int srcA, int srcB) {
    // S^T: accS[tt] holds D[krow = 16tt+4g+i][q = q16]  (scores in log2 domain)
    f32x4 accS[4] = {};
    __builtin_amdgcn_s_setprio(1);
#pragma unroll
    for (int ks = 0; ks < 2; ks++) {
#pragma unroll
        for (int tt = 0; tt < 4; tt++) {
            int row = 16 * tt + q16;
            bf16x8 ak = *(const bf16x8*)(Ks + row * 64 + ((4 * ks + g) ^ (row & 7)) * 8);
            accS[tt] = __builtin_amdgcn_mfma_f32_16x16x32_bf16(ak, qfrag[ks], accS[tt], 0, 0, 0);
        }
    }
    __builtin_amdgcn_s_setprio(0);

    float s[4][4];
#pragma unroll
    for (int tt = 0; tt < 4; tt++)
#pragma unroll
        for (int i = 0; i < 4; i++) {
            float v = accS[tt][i];
            if (diag) {
                int kg = k0 + 16 * tt + 4 * g + i;
                if (kg > myq) v = -1e30f;
            }
            s[tt][i] = v;
        }

    float pmax = s[0][0];
#pragma unroll
    for (int tt = 0; tt < 4; tt++)
#pragma unroll
        for (int i = 0; i < 4; i++) pmax = fmaxf(pmax, s[tt][i]);
    pmax = fmaxf(pmax, __shfl_xor(pmax, 16));
    pmax = fmaxf(pmax, __shfl_xor(pmax, 32));

    if (!__all(pmax <= m + 8.0f)) {          // defer-max (T13): skip rescale when growth small
        float mnew = fmaxf(m, pmax);
        float sc = EXP2(m - mnew);
        lsum *= sc;
#pragma unroll
        for (int i = 0; i < 4; i++) {
            float sci = __shfl(sc, 4 * g + i);
#pragma unroll
            for (int d = 0; d < 4; d++) acco[d][i] *= sci;
        }
        m = mnew;
    }

    float tsum = 0.f;
    float p[4][4];
#pragma unroll
    for (int tt = 0; tt < 4; tt++)
#pragma unroll
        for (int i = 0; i < 4; i++) { p[tt][i] = EXP2(s[tt][i] - m); tsum += p[tt][i]; }
    tsum += __shfl_xor(tsum, 16);
    tsum += __shfl_xor(tsum, 32);
    lsum += tsum;

    unsigned lo[4], hi[4];
#pragma unroll
    for (int tt = 0; tt < 4; tt++) {
        lo[tt] = (unsigned)f2bf(p[tt][0]) | ((unsigned)f2bf(p[tt][1]) << 16);
        hi[tt] = (unsigned)f2bf(p[tt][2]) | ((unsigned)f2bf(p[tt][3]) << 16);
    }

    // PV: two shuffle rounds (tt=2ks, 2ks+1); dest selects with its own gh after.
#pragma unroll
    for (int ks = 0; ks < 2; ks++) {
        unsigned xa0 = __shfl(lo[2 * ks], srcA);
        unsigned xa1 = __shfl(hi[2 * ks], srcA);
        unsigned xa2 = __shfl(lo[2 * ks], srcB);
        unsigned xa3 = __shfl(hi[2 * ks], srcB);
        unsigned ya0 = __shfl(lo[2 * ks + 1], srcA);
        unsigned ya1 = __shfl(hi[2 * ks + 1], srcA);
        unsigned ya2 = __shfl(lo[2 * ks + 1], srcB);
        unsigned ya3 = __shfl(hi[2 * ks + 1], srcB);
        uint4 pw;
        pw.x = gh ? ya0 : xa0;
        pw.y = gh ? ya1 : xa1;
        pw.z = gh ? ya2 : xa2;
        pw.w = gh ? ya3 : xa3;
        bf16x8 pfrag = __builtin_bit_cast(bf16x8, pw);
        __builtin_amdgcn_s_setprio(1);
#pragma unroll
        for (int d = 0; d < 4; d++) {
            int row = 16 * d + q16;
            bf16x8 vv = *(const bf16x8*)(Vs + row * 64 + ((4 * ks + g) ^ (row & 7)) * 8);
            acco[d] = __builtin_amdgcn_mfma_f32_16x16x32_bf16(pfrag, vv, acco[d], 0, 0, 0);
        }
        __builtin_amdgcn_s_setprio(0);
    }
}

// ---------------- flash attention, causal. Block bx runs q-tiles bx then 31-bx
// SEQUENTIALLY (uniform 33 k-steps/block); K/V double-buffered via global_load_lds
// with pre-swizzled source; XOR-swizzled reads.
__global__ __launch_bounds__(256) void attn_kernel(const unsigned short* __restrict__ Q,
                                                   const unsigned short* __restrict__ Kb,
                                                   const unsigned short* __restrict__ VT,
                                                   unsigned short* __restrict__ Xout) {
    __shared__ alignas(16) unsigned short Ksm[2][4096];
    __shared__ alignas(16) unsigned short Vsm[2][4096];
    const int t = threadIdx.x;
    const int lane = t & 63, w = t >> 6;
    const int g = lane >> 4, q16 = lane & 15;
    const int bh = blockIdx.y;
    const int b = bh >> 4, h = bh & 15;

    // staging: LDS(row,s16) = global(row, s16^(row&7)); row = t/8 + 32j, slot t&7
    const int srow0 = t >> 3;
    const int ssrc = ((t & 7) ^ (srow0 & 7)) * 8;
    const unsigned short* srcK[2];
    const unsigned short* srcV[2];
#pragma unroll
    for (int j = 0; j < 2; j++) {
        int row = srow0 + 32 * j;
        srcK[j] = Kb + ((size_t)bh * 2048 + row) * 64 + ssrc;    // + 4096*kt
        srcV[j] = VT + ((size_t)bh * 64 + row) * 2048 + ssrc;    // + 64*kt
    }

    const int gh = g >> 1;
    const int g0 = 2 * (g & 1);
    const int srcA = 16 * g0 + q16, srcB = srcA + 16;

#pragma unroll 1
    for (int ph = 0; ph < 2; ph++) {
        const int qt = ph ? (31 - (int)blockIdx.x) : (int)blockIdx.x;
        const int q0 = qt * 64;
        const int myq = q0 + 16 * w + q16;
        const int nkt = qt + 1;

        bf16x8 qfrag[2];
        {
            const uint4* qp = (const uint4*)(Q + ((size_t)bh * 2048 + myq) * 64);
            qfrag[0] = __builtin_bit_cast(bf16x8, qp[g]);
            qfrag[1] = __builtin_bit_cast(bf16x8, qp[4 + g]);
        }

        f32x4 acco[4] = {};
        float m = -1e30f, lsum = 0.f;
        int cur = 0;

        // prologue: stage tile 0 into buffer 0
#pragma unroll
        for (int j = 0; j < 2; j++) {
            gload_lds16(srcK[j], &Ksm[0][512 * w + 2048 * j]);
            gload_lds16(srcV[j], &Vsm[0][512 * w + 2048 * j]);
        }
        __syncthreads();

        for (int kt = 0; kt < nkt; kt++) {
            if (kt + 1 < nkt) {   // prefetch next tile into the other buffer
                int nxt = cur ^ 1;
#pragma unroll
                for (int j = 0; j < 2; j++) {
                    gload_lds16(srcK[j] + (size_t)(kt + 1) * 4096, &Ksm[nxt][512 * w + 2048 * j]);
                    gload_lds16(srcV[j] + (size_t)(kt + 1) * 64,   &Vsm[nxt][512 * w + 2048 * j]);
                }
            }
            attn_step(Ksm[cur], Vsm[cur], qfrag, acco, m, lsum,
                      myq, kt * 64, kt == nkt - 1, g, q16, gh, srcA, srcB);
            __syncthreads();   // drains prefetch vmcnt + protects buffer swap
            cur ^= 1;
        }

        // normalize and write x[B,S,D] bf16: lane holds O[q'=4g+i][dh=16d+q16]
#pragma unroll
        for (int i = 0; i < 4; i++) {
            float li = __shfl(lsum, 4 * g + i);
            float inv = 1.f / li;
            int row = q0 + 16 * w + 4 * g + i;
#pragma unroll
            for (int d = 0; d < 4; d++) {
                int col = h * 64 + 16 * d + q16;
                Xout[((size_t)b * 2048 + row) * 1024 + col] = f2bf(acco[d][i] * inv);
            }
        }
        __syncthreads();   // phase boundary: buffers reused from scratch
    }
}

extern "C" void kernel_launch(void* const* d_in, const int* in_sizes, int n_in,
                              void* d_out, int out_size, void* d_ws, size_t ws_size,
                              hipStream_t stream) {
    (void)in_sizes; (void)n_in; (void)out_size; (void)ws_size;
    const float* query = (const float*)d_in[0];
    const float* key   = (const float*)d_in[1];
    const float* value = (const float*)d_in[2];
    // d_in[3] = mask (causal tril) — implemented analytically
    const float* Wq = (const float*)d_in[4];
    const float* bq = (const float*)d_in[5];
    const float* Wk = (const float*)d_in[6];
    const float* bk = (const float*)d_in[7];
    const float* Wv = (const float*)d_in[8];
    const float* bv = (const float*)d_in[9];
    const float* Wo = (const float*)d_in[10];
    const float* bo = (const float*)d_in[11];

    char* base = (char*)d_ws;
    const size_t MB = 1u << 20;
    unsigned short* WTq = (unsigned short*)(base + 0 * MB);
    unsigned short* WTk = (unsigned short*)(base + 2 * MB);
    unsigned short* WTv = (unsigned short*)(base + 4 * MB);
    unsigned short* WTo = (unsigned short*)(base + 6 * MB);
    unsigned short* Qb  = (unsigned short*)(base + 8 * MB);
    unsigned short* Kbf = (unsigned short*)(base + 24 * MB);
    unsigned short* VTb = (unsigned short*)(base + 40 * MB);
    unsigned short* X   = (unsigned short*)(base + 56 * MB);   // q-bf16, then Xattn

    // key/value bf16 scratch in d_out (consumed by gemm_qkv before gemm_out writes d_out)
    unsigned short* Xk = (unsigned short*)d_out;
    unsigned short* Xv = Xk + (size_t)8192 * 1024;

    const int n8 = (8192 * 1024) / 8;

    transpose_weights<<<dim3(32, 32, 4), dim3(32, 8), 0, stream>>>(Wq, Wk, Wv, Wo, WTq, WTk, WTv, WTo);
    cvt3<<<dim3(4096, 1, 3), 256, 0, stream>>>(query, key, value, X, Xk, Xv, n8);
    gemm_qkv<<<dim3(8, 64, 3), 256, 0, stream>>>(X, Xk, Xv, WTq, WTk, WTv, bq, bk, bv, Qb, Kbf, VTb);
    attn_kernel<<<dim3(16, 64), 256, 0, stream>>>(Qb, Kbf, VTb, X);
    gemm_out<<<dim3(8, 64), 256, 0, stream>>>(X, WTo, bo, (float*)d_out);
}

// Round 9
// 340.706 us; speedup vs baseline: 1.1996x; 1.0102x over previous
//
#include <hip/hip_runtime.h>
#include <hip/hip_bf16.h>

// MHA: B=4, S=2048, D=1024, H=16, DH=64.  All matmuls via mfma_f32_16x16x32_bf16.
// ws (MB): WTq@0 WTk@2 WTv@4 WTo@6 | Qb@8 Kb@24 VT@40 | X@56 (q-bf16, then Xattn).
// key/value bf16 scratch lives in d_out (33.5MB), consumed before gemm_out writes it.

typedef __bf16 bf16x8 __attribute__((ext_vector_type(8)));
typedef float f32x4 __attribute__((ext_vector_type(4)));

#define GLOBAL_AS __attribute__((address_space(1)))
#define LDS_AS __attribute__((address_space(3)))

#if __has_builtin(__builtin_amdgcn_exp2f)
#define EXP2(x) __builtin_amdgcn_exp2f(x)
#else
#define EXP2(x) __expf((x) * 0.6931471805599453f)
#endif
#define QSCALE 0.18033688f   // 0.125 * log2(e): scores live in log2 domain

static __device__ __forceinline__ unsigned short f2bf(float f) {
    __bf16 h = (__bf16)f;                       // RNE
    return __builtin_bit_cast(unsigned short, h);
}

static __device__ __forceinline__ void gload_lds16(const void* g, void* l) {
    __builtin_amdgcn_global_load_lds((const GLOBAL_AS void*)g, (LDS_AS void*)l, 16, 0, 0);
}

// ---------------- fp32 -> bf16 bulk convert, 3 tensors in one launch (z selects)
__global__ __launch_bounds__(256) void cvt3(const float* __restrict__ q,
                                            const float* __restrict__ k,
                                            const float* __restrict__ v,
                                            unsigned short* __restrict__ dq,
                                            unsigned short* __restrict__ dk,
                                            unsigned short* __restrict__ dv, int n8) {
    const int z = blockIdx.z;
    const float* src = (z == 0) ? q : (z == 1) ? k : v;
    unsigned short* dst = (z == 0) ? dq : (z == 1) ? dk : dv;
    int i = blockIdx.x * 256 + threadIdx.x;
    if (i >= n8) return;
    const float4* s = (const float4*)src + 2 * (size_t)i;
    float4 v0 = s[0], v1 = s[1];
    unsigned short h[8] = {f2bf(v0.x), f2bf(v0.y), f2bf(v0.z), f2bf(v0.w),
                           f2bf(v1.x), f2bf(v1.y), f2bf(v1.z), f2bf(v1.w)};
    *(uint4*)(dst + 8 * (size_t)i) = *(const uint4*)h;
}

// ---------------- weight transpose: W fp32 [K=1024][N=1024] -> W^T bf16 [N][K]
__global__ void transpose_weights(const float* __restrict__ W0, const float* __restrict__ W1,
                                  const float* __restrict__ W2, const float* __restrict__ W3,
                                  unsigned short* __restrict__ T0, unsigned short* __restrict__ T1,
                                  unsigned short* __restrict__ T2, unsigned short* __restrict__ T3) {
    const float* W; unsigned short* T;
    switch (blockIdx.z) { case 0: W=W0; T=T0; break; case 1: W=W1; T=T1; break;
                          case 2: W=W2; T=T2; break; default: W=W3; T=T3; }
    __shared__ float tile[32][33];
    int tx = threadIdx.x, ty = threadIdx.y;
    int k0 = blockIdx.x * 32, n0 = blockIdx.y * 32;
#pragma unroll
    for (int j = 0; j < 4; j++) tile[ty + 8*j][tx] = W[(size_t)(k0 + ty + 8*j) * 1024 + n0 + tx];
    __syncthreads();
#pragma unroll
    for (int j = 0; j < 4; j++) T[(size_t)(n0 + ty + 8*j) * 1024 + k0 + tx] = f2bf(tile[tx][ty + 8*j]);
}

// ---------------- GEMM K-loop, 2-phase double-buffered + T2 XOR-swizzled LDS.
// LDS(row, slot16B) = global(row, slot ^ (row&7)); gload_lds dest stays linear,
// source col is pre-swizzled (rule #21: both-sides-or-neither).
static __device__ __forceinline__ void gemm_core(const unsigned short* __restrict__ A,
                                                 const unsigned short* __restrict__ BT,
                                                 unsigned short* Asm, unsigned short* Bsm,
                                                 int rowBase, int colBase, int t,
                                                 f32x4 acc[4][4]) {
    const int lane = t & 63, w = t >> 6;
    const int g = lane >> 4, r16 = lane & 15;
    const int wr = w >> 1, wc = w & 1;
    const int K = 1024;
    const int srow = t >> 3;                           // 0..31 (+32j); row&7 = (t>>3)&7
    const int scol = ((t & 7) ^ ((t >> 3) & 7)) * 8;   // pre-swizzled source col

    const unsigned short* srcA[4];
    const unsigned short* srcB[4];
#pragma unroll
    for (int j = 0; j < 4; j++) {
        srcA[j] = A  + (size_t)(rowBase + srow + 32 * j) * K + scol;
        srcB[j] = BT + (size_t)(colBase + srow + 32 * j) * K + scol;
    }
    unsigned short* dstA = Asm + 512 * w;   // + 8192*buf + 2048*j (linear dest)
    unsigned short* dstB = Bsm + 512 * w;

    // prologue: stage tile 0 into buffer 0
#pragma unroll
    for (int j = 0; j < 4; j++) {
        gload_lds16(srcA[j], dstA + 2048 * j);
        gload_lds16(srcB[j], dstB + 2048 * j);
    }
    __syncthreads();

    int cur = 0;
    for (int k0 = 0; k0 < K; k0 += 64) {
        if (k0 + 64 < K) {   // prefetch next tile into the other buffer
            unsigned short* dA = dstA + (cur ^ 1) * 8192;
            unsigned short* dB = dstB + (cur ^ 1) * 8192;
#pragma unroll
            for (int j = 0; j < 4; j++) {
                gload_lds16(srcA[j] + k0 + 64, dA + 2048 * j);
                gload_lds16(srcB[j] + k0 + 64, dB + 2048 * j);
            }
        }
        const unsigned short* As = Asm + cur * 8192;
        const unsigned short* Bs = Bsm + cur * 8192;
#pragma unroll
        for (int ks = 0; ks < 2; ks++) {
            bf16x8 a[4], b[4];
#pragma unroll
            for (int m = 0; m < 4; m++) {
                int row = 64 * wr + 16 * m + r16;      // row&7 = r16&7
                a[m] = *(const bf16x8*)(As + row * 64 + ((4 * ks + g) ^ (row & 7)) * 8);
            }
#pragma unroll
            for (int n = 0; n < 4; n++) {
                int row = 64 * wc + 16 * n + r16;
                b[n] = *(const bf16x8*)(Bs + row * 64 + ((4 * ks + g) ^ (row & 7)) * 8);
            }
#pragma unroll
            for (int m = 0; m < 4; m++)
#pragma unroll
                for (int n = 0; n < 4; n++)
                    acc[m][n] = __builtin_amdgcn_mfma_f32_16x16x32_bf16(a[m], b[n], acc[m][n], 0, 0, 0);
        }
        __syncthreads();   // drains prefetch vmcnt + protects buffer swap
        cur ^= 1;
    }
}

// ---------------- fused Q/K/V projection GEMM (z: 0=Q scaled, 1=K, 2=V^T)
__global__ __launch_bounds__(256) void gemm_qkv(
        const unsigned short* __restrict__ Xq, const unsigned short* __restrict__ Xk,
        const unsigned short* __restrict__ Xv,
        const unsigned short* __restrict__ WTq, const unsigned short* __restrict__ WTk,
        const unsigned short* __restrict__ WTv,
        const float* __restrict__ bq, const float* __restrict__ bk, const float* __restrict__ bv,
        unsigned short* __restrict__ Qb, unsigned short* __restrict__ Kb,
        unsigned short* __restrict__ VT) {
    __shared__ alignas(16) unsigned short smem[32768];   // A dbuf | B dbuf; reused for V^T transpose
    unsigned short* Asm = smem;
    unsigned short* Bsm = smem + 16384;
    const int z = blockIdx.z;
    const unsigned short* A  = (z == 0) ? Xq : (z == 1) ? Xk : Xv;
    const unsigned short* BT = (z == 0) ? WTq : (z == 1) ? WTk : WTv;
    const float* bias        = (z == 0) ? bq : (z == 1) ? bk : bv;
    const int rowBase = blockIdx.y * 128, colBase = blockIdx.x * 128;
    const int t = threadIdx.x;
    const int lane = t & 63, w = t >> 6;
    const int g = lane >> 4, r16 = lane & 15;
    const int wr = w >> 1, wc = w & 1;

    f32x4 acc[4][4] = {};
    gemm_core(A, BT, Asm, Bsm, rowBase, colBase, t, acc);

    float bv4[4];
#pragma unroll
    for (int n = 0; n < 4; n++) bv4[n] = bias[colBase + 64 * wc + 16 * n + r16];

    if (z == 2) {
        // V^T epilogue: transpose 128x128 tile in LDS (padded stride), coalesced stores.
        const int TS = 136;   // pad: breaks 256B-stride bank pattern; rows stay 16B-aligned
        unsigned short* Tsm = smem;   // 128*136*2B = 34.8KB <= 64KB (K-loop done)
#pragma unroll
        for (int m = 0; m < 4; m++) {
#pragma unroll
            for (int n = 0; n < 4; n++) {
                int c = 64 * wc + 16 * n + r16;            // d-dim local
                int r = 64 * wr + 16 * m + 4 * g;          // s-dim local (i = 0..3)
                unsigned short pk[4];
#pragma unroll
                for (int i = 0; i < 4; i++) pk[i] = f2bf(acc[m][n][i] + bv4[n]);
                *(uint2*)(Tsm + c * TS + r) = *(const uint2*)pk;   // 8B, aligned (r%4==0)
            }
        }
        __syncthreads();
        const int bidx = rowBase >> 11;
        const int sBase = rowBase & 2047;   // within-batch seq position
        const int sloc = (t & 15) * 8;
#pragma unroll
        for (int jj = 0; jj < 8; jj++) {
            int dloc = (t >> 4) + 16 * jj;
            uint4 v = *(const uint4*)(Tsm + dloc * TS + sloc);
            int col = colBase + dloc;
            int hidx = col >> 6, dh = col & 63;
            *(uint4*)&VT[(((size_t)(bidx * 16 + hidx)) * 64 + dh) * 2048 + sBase + sloc] = v;
        }
    } else {
#pragma unroll
        for (int m = 0; m < 4; m++) {
#pragma unroll
            for (int n = 0; n < 4; n++) {
#pragma unroll
                for (int i = 0; i < 4; i++) {
                    int row = rowBase + 64 * wr + 16 * m + 4 * g + i;
                    int col = colBase + 64 * wc + 16 * n + r16;
                    float v = acc[m][n][i] + bv4[n];
                    int bidx = row >> 11, s = row & 2047;
                    int hidx = col >> 6, dh = col & 63;
                    size_t bh = (size_t)(bidx * 16 + hidx);
                    if (z == 0) Qb[(bh * 2048 + s) * 64 + dh] = f2bf(v * QSCALE);
                    else        Kb[(bh * 2048 + s) * 64 + dh] = f2bf(v);
                }
            }
        }
    }
}

// ---------------- output projection GEMM: fp32 out
__global__ __launch_bounds__(256) void gemm_out(const unsigned short* __restrict__ A,
                                                const unsigned short* __restrict__ BT,
                                                const float* __restrict__ bias,
                                                float* __restrict__ Out) {
    __shared__ alignas(16) unsigned short smem[32768];
    unsigned short* Asm = smem;
    unsigned short* Bsm = smem + 16384;
    const int rowBase = blockIdx.y * 128, colBase = blockIdx.x * 128;
    const int t = threadIdx.x;
    const int lane = t & 63, w = t >> 6;
    const int g = lane >> 4, r16 = lane & 15;
    const int wr = w >> 1, wc = w & 1;

    f32x4 acc[4][4] = {};
    gemm_core(A, BT, Asm, Bsm, rowBase, colBase, t, acc);

    float bv4[4];
#pragma unroll
    for (int n = 0; n < 4; n++) bv4[n] = bias[colBase + 64 * wc + 16 * n + r16];

#pragma unroll
    for (int m = 0; m < 4; m++)
#pragma unroll
        for (int n = 0; n < 4; n++)
#pragma unroll
            for (int i = 0; i < 4; i++) {
                int row = rowBase + 64 * wr + 16 * m + 4 * g + i;
                int col = colBase + 64 * wc + 16 * n + r16;
                Out[(size_t)row * 1024 + col] = acc[m][n][i] + bv4[n];
            }
}

// ---------------- flash attention step for one q-state on the staged k-tile
static __device__ __forceinline__ void attn_step(
        const unsigned short* __restrict__ Ks, const unsigned short* __restrict__ Vs,
        const bf16x8 qfrag[2], f32x4 acco[4], float& m, float& lsum,
        int myq, int k0, bool diag,
        int g, int q16, int gh, int srcA, int srcB) {
    // S^T: accS[tt] holds D[krow = 16tt+4g+i][q = q16]  (scores in log2 domain)
    f32x4 accS[4] = {};
    __builtin_amdgcn_s_setprio(1);
#pragma unroll
    for (int ks = 0; ks < 2; ks++) {
#pragma unroll
        for (int tt = 0; tt < 4; tt++) {
            int row = 16 * tt + q16;
            bf16x8 ak = *(const bf16x8*)(Ks + row * 64 + ((4 * ks + g) ^ (row & 7)) * 8);
            accS[tt] = __builtin_amdgcn_mfma_f32_16x16x32_bf16(ak, qfrag[ks], accS[tt], 0, 0, 0);
        }
    }
    __builtin_amdgcn_s_setprio(0);

    float s[4][4];
#pragma unroll
    for (int tt = 0; tt < 4; tt++)
#pragma unroll
        for (int i = 0; i < 4; i++) {
            float v = accS[tt][i];
            if (diag) {
                int kg = k0 + 16 * tt + 4 * g + i;
                if (kg > myq) v = -1e30f;
            }
            s[tt][i] = v;
        }

    float pmax = s[0][0];
#pragma unroll
    for (int tt = 0; tt < 4; tt++)
#pragma unroll
        for (int i = 0; i < 4; i++) pmax = fmaxf(pmax, s[tt][i]);
    pmax = fmaxf(pmax, __shfl_xor(pmax, 16));
    pmax = fmaxf(pmax, __shfl_xor(pmax, 32));

    if (!__all(pmax <= m + 8.0f)) {          // defer-max (T13): skip rescale when growth small
        float mnew = fmaxf(m, pmax);
        float sc = EXP2(m - mnew);
        lsum *= sc;
#pragma unroll
        for (int i = 0; i < 4; i++) {
            float sci = __shfl(sc, 4 * g + i);
#pragma unroll
            for (int d = 0; d < 4; d++) acco[d][i] *= sci;
        }
        m = mnew;
    }

    float tsum = 0.f;
    float p[4][4];
#pragma unroll
    for (int tt = 0; tt < 4; tt++)
#pragma unroll
        for (int i = 0; i < 4; i++) { p[tt][i] = EXP2(s[tt][i] - m); tsum += p[tt][i]; }
    tsum += __shfl_xor(tsum, 16);
    tsum += __shfl_xor(tsum, 32);
    lsum += tsum;

    unsigned lo[4], hi[4];
#pragma unroll
    for (int tt = 0; tt < 4; tt++) {
        lo[tt] = (unsigned)f2bf(p[tt][0]) | ((unsigned)f2bf(p[tt][1]) << 16);
        hi[tt] = (unsigned)f2bf(p[tt][2]) | ((unsigned)f2bf(p[tt][3]) << 16);
    }

    // PV: two shuffle rounds (tt=2ks, 2ks+1); dest selects with its own gh after.
#pragma unroll
    for (int ks = 0; ks < 2; ks++) {
        unsigned xa0 = __shfl(lo[2 * ks], srcA);
        unsigned xa1 = __shfl(hi[2 * ks], srcA);
        unsigned xa2 = __shfl(lo[2 * ks], srcB);
        unsigned xa3 = __shfl(hi[2 * ks], srcB);
        unsigned ya0 = __shfl(lo[2 * ks + 1], srcA);
        unsigned ya1 = __shfl(hi[2 * ks + 1], srcA);
        unsigned ya2 = __shfl(lo[2 * ks + 1], srcB);
        unsigned ya3 = __shfl(hi[2 * ks + 1], srcB);
        uint4 pw;
        pw.x = gh ? ya0 : xa0;
        pw.y = gh ? ya1 : xa1;
        pw.z = gh ? ya2 : xa2;
        pw.w = gh ? ya3 : xa3;
        bf16x8 pfrag = __builtin_bit_cast(bf16x8, pw);
        __builtin_amdgcn_s_setprio(1);
#pragma unroll
        for (int d = 0; d < 4; d++) {
            int row = 16 * d + q16;
            bf16x8 vv = *(const bf16x8*)(Vs + row * 64 + ((4 * ks + g) ^ (row & 7)) * 8);
            acco[d] = __builtin_amdgcn_mfma_f32_16x16x32_bf16(pfrag, vv, acco[d], 0, 0, 0);
        }
        __builtin_amdgcn_s_setprio(0);
    }
}

// ---------------- flash attention, causal. 512-thread blocks: 8 waves, each owning
// ONE 16-row q-state; 128 q-rows/block share one K/V stream. Block runs q128-tiles
// qp then 15-qp sequentially (uniform 34 k-steps). XCD-locality swizzle: all 8
// blocks of a head share wgid%8 -> one XCD serves only 8 heads (8MB vs 67MB).
__global__ __launch_bounds__(512) void attn_kernel(const unsigned short* __restrict__ Q,
                                                   const unsigned short* __restrict__ Kb,
                                                   const unsigned short* __restrict__ VT,
                                                   unsigned short* __restrict__ Xout) {
    __shared__ alignas(16) unsigned short Ksm[2][4096];
    __shared__ alignas(16) unsigned short Vsm[2][4096];
    const int t = threadIdx.x;
    const int lane = t & 63, w = t >> 6;           // w = 0..7
    const int g = lane >> 4, q16 = lane & 15;
    const unsigned wgid = blockIdx.x;
    const int bh = 8 * (wgid & 7) + ((wgid >> 3) & 7);   // same bh -> same wgid%8 (XCD)
    const int qp = wgid >> 6;                             // 0..7
    const int b = bh >> 4, h = bh & 15;

    // staging: one 64x64 K tile + one 64x64 V^T tile per k-step; 512 thr x 16B = 8KB each.
    // LDS(row, s16) = global(row, s16^(row&7)); row = t>>3 (0..63), slot t&7.
    const int srow = t >> 3;
    const int ssrc = ((t & 7) ^ (srow & 7)) * 8;
    const unsigned short* srcK = Kb + ((size_t)bh * 2048 + srow) * 64 + ssrc;    // + 4096*kt
    const unsigned short* srcV = VT + ((size_t)bh * 64 + srow) * 2048 + ssrc;    // + 64*kt

    const int gh = g >> 1;
    const int g0 = 2 * (g & 1);
    const int srcA = 16 * g0 + q16, srcB = srcA + 16;

#pragma unroll 1
    for (int ph = 0; ph < 2; ph++) {
        const int qt128 = ph ? (15 - qp) : qp;
        const int myq = qt128 * 128 + 16 * w + q16;
        const int nkt = 2 * qt128 + 2;                 // k-tiles of 64 covering 128(qt128+1) rows
        const int diagKt = 2 * qt128 + (w >> 2);       // this wave's diagonal k-tile

        bf16x8 qfrag[2];
        {
            const uint4* qp_ = (const uint4*)(Q + ((size_t)bh * 2048 + myq) * 64);
            qfrag[0] = __builtin_bit_cast(bf16x8, qp_[g]);
            qfrag[1] = __builtin_bit_cast(bf16x8, qp_[4 + g]);
        }

        f32x4 acco[4] = {};
        float m = -1e30f, lsum = 0.f;
        int cur = 0;

        // prologue: stage tile 0 into buffer 0 (each wave writes 1KB at 512*w)
        gload_lds16(srcK, &Ksm[0][512 * w]);
        gload_lds16(srcV, &Vsm[0][512 * w]);
        __syncthreads();

        for (int kt = 0; kt < nkt; kt++) {
            if (kt + 1 < nkt) {   // prefetch next tile into the other buffer
                int nxt = cur ^ 1;
                gload_lds16(srcK + (size_t)(kt + 1) * 4096, &Ksm[nxt][512 * w]);
                gload_lds16(srcV + (size_t)(kt + 1) * 64,   &Vsm[nxt][512 * w]);
            }
            if (kt <= diagKt)     // tiles past the wave's diagonal are fully masked: skip
                attn_step(Ksm[cur], Vsm[cur], qfrag, acco, m, lsum,
                          myq, kt * 64, kt == diagKt, g, q16, gh, srcA, srcB);
            __syncthreads();   // drains prefetch vmcnt + protects buffer swap
            cur ^= 1;
        }

        // normalize and write x[B,S,D] bf16: lane holds O[q'=4g+i][dh=16d+q16]
#pragma unroll
        for (int i = 0; i < 4; i++) {
            float li = __shfl(lsum, 4 * g + i);
            float inv = 1.f / li;
            int row = qt128 * 128 + 16 * w + 4 * g + i;
#pragma unroll
            for (int d = 0; d < 4; d++) {
                int col = h * 64 + 16 * d + q16;
                Xout[((size_t)b * 2048 + row) * 1024 + col] = f2bf(acco[d][i] * inv);
            }
        }
        __syncthreads();   // phase boundary: buffers reused from scratch
    }
}

extern "C" void kernel_launch(void* const* d_in, const int* in_sizes, int n_in,
                              void* d_out, int out_size, void* d_ws, size_t ws_size,
                              hipStream_t stream) {
    (void)in_sizes; (void)n_in; (void)out_size; (void)ws_size;
    const float* query = (const float*)d_in[0];
    const float* key   = (const float*)d_in[1];
    const float* value = (const float*)d_in[2];
    // d_in[3] = mask (causal tril) — implemented analytically
    const float* Wq = (const float*)d_in[4];
    const float* bq = (const float*)d_in[5];
    const float* Wk = (const float*)d_in[6];
    const float* bk = (const float*)d_in[7];
    const float* Wv = (const float*)d_in[8];
    const float* bv = (const float*)d_in[9];
    const float* Wo = (const float*)d_in[10];
    const float* bo = (const float*)d_in[11];

    char* base = (char*)d_ws;
    const size_t MB = 1u << 20;
    unsigned short* WTq = (unsigned short*)(base + 0 * MB);
    unsigned short* WTk = (unsigned short*)(base + 2 * MB);
    unsigned short* WTv = (unsigned short*)(base + 4 * MB);
    unsigned short* WTo = (unsigned short*)(base + 6 * MB);
    unsigned short* Qb  = (unsigned short*)(base + 8 * MB);
    unsigned short* Kbf = (unsigned short*)(base + 24 * MB);
    unsigned short* VTb = (unsigned short*)(base + 40 * MB);
    unsigned short* X   = (unsigned short*)(base + 56 * MB);   // q-bf16, then Xattn

    // key/value bf16 scratch in d_out (consumed by gemm_qkv before gemm_out writes d_out)
    unsigned short* Xk = (unsigned short*)d_out;
    unsigned short* Xv = Xk + (size_t)8192 * 1024;

    const int n8 = (8192 * 1024) / 8;

    transpose_weights<<<dim3(32, 32, 4), dim3(32, 8), 0, stream>>>(Wq, Wk, Wv, Wo, WTq, WTk, WTv, WTo);
    cvt3<<<dim3(4096, 1, 3), 256, 0, stream>>>(query, key, value, X, Xk, Xv, n8);
    gemm_qkv<<<dim3(8, 64, 3), 256, 0, stream>>>(X, Xk, Xv, WTq, WTk, WTv, bq, bk, bv, Qb, Kbf, VTb);
    attn_kernel<<<512, 512, 0, stream>>>(Qb, Kbf, VTb, X);
    gemm_out<<<dim3(8, 64), 256, 0, stream>>>(X, WTo, bo, (float*)d_out);
}